// Round 8
// baseline (4190.960 us; speedup 1.0000x reference)
//
#include <hip/hip_runtime.h>
#include <hip/hip_bf16.h>

// SimpleLSTM on MI355X — round 11: fused lag-pipelining (2 recurrences/sync).
//   B=64, S=512, I=512, H=1024, gates = 4H = 4096
// R7-R10 post-mortem: all poll-microstructure variants land at 2.3-2.5ms;
// per-sync-round cost (~3.5us: fabric latency + queueing + 32-producer skew)
// is structure-insensitive. So: HALVE THE SYNC ROUNDS PER STEP.
// R11: 4 cohorts x 64 slots. Each block serves TWO batch-groups with the SAME
// weights (weights depend only on slot): group g0=2p at step m in A-rows 0-7,
// group g1=2p+1 at step m-1 in A-rows 8-15 — fused into ONE MFMA pass, one
// poll, one barrier, one elementwise, one publish per macro-step. g1's h-dep
// is a full macro old (always ready); only g0's recency is exposed, amortized
// over 2 steps. Slot owns 16 h-cols (64 gate-cols); wave w owns h-K
// [128w,+128) = producer slots [8w,8w+8). wx fits in regs now (no wxl LDS);
// all 64 lanes carry A-rows (R8 idled half). gtile stride-20 rows -> 2-way
// bank alias only (free); double-buffered -> ONE barrier per macro.
// Unchanged proven mechanics: agent-scope relaxed atomics, epoch-in-data
// tags (tag = step+1), transitive buffer-reuse safety within each cohort.

#define BATCH 64
#define SEQ   512
#define ISZ   512
#define HSZ   1024
#define G4    4096

#define NGRP  8
#define GB    8      // batches per group
#define SLOTS 64     // blocks per cohort; slot owns 16 h-cols

typedef short bf16x8 __attribute__((ext_vector_type(8)));
typedef float f32x4  __attribute__((ext_vector_type(4)));

#define HEX_DW (NGRP * 2 * GB * HSZ)   // 131072 tagged dwords = 512 KB

static __device__ __forceinline__ short f2bf(float f) {
    __hip_bfloat16 h = __float2bfloat16(f);
    return *reinterpret_cast<short*>(&h);
}
static __device__ __forceinline__ float sigm(float x) {
    return 1.f / (1.f + __expf(-x));
}
static __device__ __forceinline__ float tanh_fast(float x) {
    x = fminf(15.f, fmaxf(-15.f, x));
    float e = __expf(2.f * x);
    return (e - 1.f) / (e + 1.f);
}

__global__ __launch_bounds__(512, 2) void lstm_persistent(
    const float* __restrict__ x,     // [B][S][I] fp32
    const float* __restrict__ W,     // [I+H][4H] fp32
    const float* __restrict__ bias,  // [4H] fp32
    float* __restrict__ out,         // [B][S][H], then [B][H] h, [B][H] c
    unsigned int* __restrict__ hx)   // [NGRP][2][GB][HSZ] tagged words
{
    const int tid  = threadIdx.x;
    const int bid  = blockIdx.x;
    const int p    = bid & 3;           // cohort 0..3 (serves groups 2p, 2p+1)
    const int s    = bid >> 2;          // slot 0..63: owns h-cols [16s, 16s+16)
    const int w    = tid >> 6;          // wave 0..7 = h-K slice [128w, +128)
    const int lane = tid & 63;
    const int m16  = lane & 15;
    const int quad = lane >> 4;

    // gtile[buf][wave][gate][gihalf][row][20]: stride 20 -> writes/reads are
    // 2-way bank-aliased only (free). 80 KB; + pad forces 1 block/CU.
    __shared__ float gtile[2][8][4][2][8][20];
    __shared__ float pad_[4096];            // 16 KB -> LDS total 96 KB
    { volatile float* pp = pad_; pp[tid] = 0.f; }   // keep allocation alive

    // ---- preload weights as MFMA B-fragments (all register-resident) ----
    // B-frag (16x16x32): lane holds B[k = quad*8 + j][n = m16]
    bf16x8 wh[4][4];   // [gate][kk]: Wh[w*128 + kk*32 ..][gate*1024 + s*16 ..+16)
    bf16x8 wx[4][2];   // [gate][kk]: Wx[w*64  + kk*32 ..][same cols]
    #pragma unroll
    for (int gg = 0; gg < 4; ++gg) {
        const int col = gg * 1024 + s * 16 + m16;
        #pragma unroll
        for (int kk = 0; kk < 4; ++kk)
            #pragma unroll
            for (int j = 0; j < 8; ++j)
                wh[gg][kk][j] = f2bf(W[(size_t)(ISZ + w * 128 + kk * 32 + quad * 8 + j) * G4 + col]);
        #pragma unroll
        for (int kk = 0; kk < 2; ++kk)
            #pragma unroll
            for (int j = 0; j < 8; ++j)
                wx[gg][kk][j] = f2bf(W[(size_t)(w * 64 + kk * 32 + quad * 8 + j) * G4 + col]);
    }

    // elementwise mapping (tid < 256): egi = group half, eb = batch, ec = col
    const int egi = tid >> 7;
    const int eb  = (tid >> 4) & 7;
    const int ec  = tid & 15;
    float bia[4];
    #pragma unroll
    for (int gg = 0; gg < 4; ++gg) bia[gg] = bias[gg * 1024 + s * 16 + ec];
    float c_state = 0.f;

    f32x4 acc[4];
    f32x4 xr0 = {0,0,0,0}, xr1 = {0,0,0,0}, xr2 = {0,0,0,0}, xr3 = {0,0,0,0};

    // x loads feeding macro mm: A-rows 0-7 = x[g0 @ step mm], rows 8-15 = x[g1 @ mm-1]
    auto xload = [&](int mm) {
        const int gi = m16 >> 3;
        const int t  = gi ? (mm - 1) : mm;
        xr0 = (f32x4){0,0,0,0}; xr1 = xr0; xr2 = xr0; xr3 = xr0;
        if (t >= 0 && t < SEQ) {
            const int batch = (2 * p + gi) * 8 + (m16 & 7);
            const float* xp = x + ((size_t)batch * SEQ + t) * ISZ + w * 64 + quad * 8;
            xr0 = *(const f32x4*)xp;
            xr1 = *(const f32x4*)(xp + 4);
            xr2 = *(const f32x4*)(xp + 32);
            xr3 = *(const f32x4*)(xp + 36);
        }
    };
    auto xmfma = [&]() {
        #pragma unroll
        for (int gg = 0; gg < 4; ++gg) acc[gg] = (f32x4){0.f, 0.f, 0.f, 0.f};
        bf16x8 a0, a1;
        a0[0]=f2bf(xr0[0]); a0[1]=f2bf(xr0[1]); a0[2]=f2bf(xr0[2]); a0[3]=f2bf(xr0[3]);
        a0[4]=f2bf(xr1[0]); a0[5]=f2bf(xr1[1]); a0[6]=f2bf(xr1[2]); a0[7]=f2bf(xr1[3]);
        a1[0]=f2bf(xr2[0]); a1[1]=f2bf(xr2[1]); a1[2]=f2bf(xr2[2]); a1[3]=f2bf(xr2[3]);
        a1[4]=f2bf(xr3[0]); a1[5]=f2bf(xr3[1]); a1[6]=f2bf(xr3[2]); a1[7]=f2bf(xr3[3]);
        #pragma unroll
        for (int gg = 0; gg < 4; ++gg)
            acc[gg] = __builtin_amdgcn_mfma_f32_16x16x32_bf16(a0, wx[gg][0], acc[gg], 0, 0, 0);
        #pragma unroll
        for (int gg = 0; gg < 4; ++gg)
            acc[gg] = __builtin_amdgcn_mfma_f32_16x16x32_bf16(a1, wx[gg][1], acc[gg], 0, 0, 0);
    };

    xload(0);
    xmfma();   // acc = x-part for macro 0 (g1 rows zero: step -1)

    // macro m computes g0 @ m (rows 0-7) and g1 @ m-1 (rows 8-15)
    for (int m = 0; m <= SEQ; ++m) {
        if (m < SEQ) xload(m + 1);   // HBM latency hides under poll+MFMA+ew

        // ---- fused poll + load h (per-lane group/buffer/tag) ----
        // g0 rows: h_g0@{m-1}, buf (m+1)&1, tag m (published macro m-1)
        // g1 rows: h_g1@{m-2}, buf  m&1,    tag m-1 (a full macro old)
        {
            const int gi  = m16 >> 3;
            const int buf = gi ? (m & 1) : ((m + 1) & 1);
            const unsigned int tg =
                (unsigned int)(gi ? (m > 0 ? m - 1 : 0) : m) & 0xFFFFu;
            const unsigned long long* hp64 = (const unsigned long long*)
                (hx + ((size_t)(2 * p + gi) * 2 * GB + (size_t)buf * GB + (m16 & 7)) * HSZ
                    + w * 128 + quad * 8);

            unsigned long long cb[4][4];
            long long guard = 0;
            for (;;) {
                unsigned int bad = 0;
                #pragma unroll
                for (int kk = 0; kk < 4; ++kk)
                    #pragma unroll
                    for (int j = 0; j < 4; ++j) {
                        cb[kk][j] = __hip_atomic_load(hp64 + kk * 16 + j,
                            __ATOMIC_RELAXED, __HIP_MEMORY_SCOPE_AGENT);
                        bad |= ((unsigned int)cb[kk][j] ^ tg)
                             | ((unsigned int)(cb[kk][j] >> 32) ^ tg);
                    }
                if (__all((int)((bad & 0xFFFFu) == 0u))) break;
                __builtin_amdgcn_s_sleep(1);
                if (++guard > (1LL << 22)) break;   // safety valve (never trips)
            }
            #pragma unroll
            for (int kk = 0; kk < 4; ++kk) {
                bf16x8 ha;
                #pragma unroll
                for (int j = 0; j < 4; ++j) {
                    ha[2 * j]     = (short)((unsigned int)cb[kk][j] >> 16);
                    ha[2 * j + 1] = (short)(cb[kk][j] >> 48);
                }
                #pragma unroll
                for (int gg = 0; gg < 4; ++gg)
                    acc[gg] = __builtin_amdgcn_mfma_f32_16x16x32_bf16(ha, wh[gg][kk], acc[gg], 0, 0, 0);
            }
        }

        // ---- partials -> LDS (D: row = quad*4+r = batch-half, col = m16) ----
        {
            const int gih = quad >> 1;
            const int r0  = (quad & 1) * 4;
            #pragma unroll
            for (int gg = 0; gg < 4; ++gg)
                #pragma unroll
                for (int r = 0; r < 4; ++r)
                    gtile[m & 1][w][gg][gih][r0 + r][m16] = acc[gg][r];
        }
        __syncthreads();   // the only barrier per macro (gtile double-buffered)

        // ---- elementwise gates + publish + out (both groups, 256 threads) ----
        if (tid < 256) {
            const int st = egi ? (m - 1) : m;   // this half's step
            if (st >= 0 && st < SEQ) {          // wave-uniform guard
                float gv[4];
                #pragma unroll
                for (int gg = 0; gg < 4; ++gg) {
                    float ss = bia[gg];
                    #pragma unroll
                    for (int ww = 0; ww < 8; ++ww)
                        ss += gtile[m & 1][ww][gg][egi][eb][ec];
                    gv[gg] = ss;
                }
                float f  = sigm(gv[0]);
                float i  = sigm(gv[1]);
                float cc = tanh_fast(gv[2]);
                float o  = sigm(gv[3]);
                c_state  = f * c_state + i * cc;
                float h_val = o * tanh_fast(c_state);
                unsigned int pword = ((unsigned int)(unsigned short)f2bf(h_val) << 16)
                                   | ((unsigned int)(st + 1) & 0xFFFFu);
                unsigned int nw = __shfl_xor(pword, 1, 64);
                const int gsel = 2 * p + egi;
                if (!(ec & 1)) {
                    unsigned long long pk = (unsigned long long)pword
                                          | ((unsigned long long)nw << 32);
                    __hip_atomic_store(
                        (unsigned long long*)(hx + ((size_t)gsel * 2 * GB
                            + (size_t)(st & 1) * GB + eb) * HSZ + s * 16 + ec),
                        pk, __ATOMIC_RELAXED, __HIP_MEMORY_SCOPE_AGENT);
                }
                const int batch = gsel * 8 + eb;
                out[((size_t)batch * SEQ + st) * HSZ + s * 16 + ec] = h_val;
                if (st == SEQ - 1) {
                    size_t fin = (size_t)BATCH * SEQ * HSZ;
                    out[fin + (size_t)batch * HSZ + s * 16 + ec] = h_val;
                    out[fin + (size_t)BATCH * HSZ + (size_t)batch * HSZ
                            + s * 16 + ec] = c_state;
                }
            }
        }

        // ---- x part for macro m+1 from prefetched regs ----
        if (m < SEQ) xmfma();
    }
}

extern "C" void kernel_launch(void* const* d_in, const int* in_sizes, int n_in,
                              void* d_out, int out_size, void* d_ws, size_t ws_size,
                              hipStream_t stream) {
    const float* x    = (const float*)d_in[0];
    const float* W    = (const float*)d_in[1];
    const float* bias = (const float*)d_in[2];
    float* out        = (float*)d_out;

    unsigned int* hx = (unsigned int*)d_ws;

    // zero tagged exchange: epoch 0 == valid h(-1) = 0 for both groups/buffers
    hipMemsetAsync(d_ws, 0, HEX_DW * 4, stream);

    lstm_persistent<<<256, 512, 0, stream>>>(x, W, bias, out, hx);
}

// Round 9
// 3906.974 us; speedup vs baseline: 1.0727x; 1.0727x over previous
//
#include <hip/hip_runtime.h>
#include <hip/hip_bf16.h>

// SimpleLSTM on MI355X — round 12: alternating-phase dual-group blocks.
//   B=64, S=512, I=512, H=1024, gates = 4H = 4096
// R11 post-mortem: lag-fused dual groups did NOT halve sync rounds (groups
// were already parallel; sequential depth = rounds per group's own chain).
// 2359 -> 4191us. Reverted.
// R12: keep two groups per block (weights shared!) but run them as
// ALTERNATING PHASES: publish_A(m) -> poll_A(m+1) has the whole B-phase in
// between, so each group's store->visibility latency hides under the other
// group's compute. Since h data is a full phase old at poll time, issue ALL
// 16 tagged loads at once (one round trip; R9's stale-first-check flaw only
// applied when producers hadn't published yet).
//   * 4 cohorts x 64 slots; block serves groups 2p (phase A), 2p+1 (phase B)
//   * slot owns 16 cols/gate (64 gate-cols): wh 64 + wx 32 VGPRs, no LDS wxl
//   * wave w polls producers [8w,8w+8) -> block collectively polls all 64
//     producers before its barrier -> publish-after-barrier keeps the
//     transitive buffer-reuse safety proof from R8
//   * gtile[2] phase-alternating buffers -> 1 barrier per phase (= per step);
//     stride-20 rows make the MFMA->LDS writes bank-conflict-free
//   * LDS padded to 84KB -> 1 block/CU guaranteed; launch_bounds(512,2)
//   Unchanged proven mechanics: agent-scope relaxed atomics, epoch-in-data
//   tags (tag = step+1), buf = step&1, x prefetched a phase ahead.

#define BATCH 64
#define SEQ   512
#define ISZ   512
#define HSZ   1024
#define G4    4096

#define NGRP  8
#define GB    8      // batches per group

typedef short bf16x8 __attribute__((ext_vector_type(8)));
typedef float f32x4  __attribute__((ext_vector_type(4)));

#define HEX_DW (NGRP * 2 * GB * HSZ)   // 131072 tagged dwords = 512 KB

static __device__ __forceinline__ short f2bf(float f) {
    __hip_bfloat16 h = __float2bfloat16(f);
    return *reinterpret_cast<short*>(&h);
}
static __device__ __forceinline__ float sigm(float x) {
    return 1.f / (1.f + __expf(-x));
}
static __device__ __forceinline__ float tanh_fast(float x) {
    x = fminf(15.f, fmaxf(-15.f, x));
    float e = __expf(2.f * x);
    return (e - 1.f) / (e + 1.f);
}

__global__ __launch_bounds__(512, 2) void lstm_persistent(
    const float* __restrict__ x,     // [B][S][I] fp32
    const float* __restrict__ W,     // [I+H][4H] fp32
    const float* __restrict__ bias,  // [4H] fp32
    float* __restrict__ out,         // [B][S][H], then [B][H] h, [B][H] c
    unsigned int* __restrict__ hx)   // [NGRP][2][GB][HSZ] tagged words
{
    const int tid  = threadIdx.x;
    const int bid  = blockIdx.x;
    const int p    = bid & 3;           // cohort: serves groups 2p, 2p+1
    const int s    = bid >> 2;          // slot 0..63: owns 16 cols per gate
    const int w    = tid >> 6;          // wave 0..7 = h-K slice [128w, +128)
    const int lane = tid & 63;
    const int m16  = lane & 15;
    const int quad = lane >> 4;

    // [buf][wave][gate][row][20]: stride 20 -> MFMA D writes conflict-free
    __shared__ float gtile[2][8][4][8][20];   // 40 KB
    __shared__ float pad_[11264];             // 44 KB -> 84 KB total: 1 block/CU
    { volatile float* pp = pad_; pp[tid] = 0.f; }

    // ---- preload weights as MFMA B-fragments (all register-resident) ----
    // B-frag (16x16x32): lane holds B[k = quad*8 + j][n = m16]
    bf16x8 wh[4][4];   // [gate][kk]: Wh rows [w*128 + kk*32 ..), cols gg*1024+s*16..+16
    bf16x8 wx[4][2];   // [gate][kk]: Wx rows [w*64  + kk*32 ..), same cols
    #pragma unroll
    for (int gg = 0; gg < 4; ++gg) {
        const int col = gg * 1024 + s * 16 + m16;
        #pragma unroll
        for (int kk = 0; kk < 4; ++kk)
            #pragma unroll
            for (int j = 0; j < 8; ++j)
                wh[gg][kk][j] = f2bf(W[(size_t)(ISZ + w * 128 + kk * 32 + quad * 8 + j) * G4 + col]);
        #pragma unroll
        for (int kk = 0; kk < 2; ++kk)
            #pragma unroll
            for (int j = 0; j < 8; ++j)
                wx[gg][kk][j] = f2bf(W[(size_t)(w * 64 + kk * 32 + quad * 8 + j) * G4 + col]);
    }

    // elementwise mapping (tid < 128): eb = batch, ec = col-in-16
    const int eb = tid >> 4;
    const int ec = tid & 15;
    float bia[4] = {0.f, 0.f, 0.f, 0.f};
    if (tid < 128) {
        #pragma unroll
        for (int gg = 0; gg < 4; ++gg) bia[gg] = bias[gg * 1024 + s * 16 + ec];
    }
    float c_st0 = 0.f, c_st1 = 0.f;     // per-phase cell states (static names)

    f32x4 acc[4];
    f32x4 xr0 = {0,0,0,0}, xr1 = {0,0,0,0}, xr2 = {0,0,0,0}, xr3 = {0,0,0,0};

    // load x for (group 2p+gi, step t) into xr (this wave's x-K slice)
    auto xload = [&](int gi, int t) {
        if (t < SEQ && m16 < 8) {
            const int batch = (2 * p + gi) * 8 + m16;
            const float* xp = x + ((size_t)batch * SEQ + t) * ISZ + w * 64 + quad * 8;
            xr0 = *(const f32x4*)xp;
            xr1 = *(const f32x4*)(xp + 4);
            xr2 = *(const f32x4*)(xp + 32);
            xr3 = *(const f32x4*)(xp + 36);
        }
    };
    // acc = x @ Wx from prefetched regs (resets acc)
    auto xmfma = [&]() {
        #pragma unroll
        for (int gg = 0; gg < 4; ++gg) acc[gg] = (f32x4){0.f, 0.f, 0.f, 0.f};
        bf16x8 a0, a1;
        a0[0]=f2bf(xr0[0]); a0[1]=f2bf(xr0[1]); a0[2]=f2bf(xr0[2]); a0[3]=f2bf(xr0[3]);
        a0[4]=f2bf(xr1[0]); a0[5]=f2bf(xr1[1]); a0[6]=f2bf(xr1[2]); a0[7]=f2bf(xr1[3]);
        a1[0]=f2bf(xr2[0]); a1[1]=f2bf(xr2[1]); a1[2]=f2bf(xr2[2]); a1[3]=f2bf(xr2[3]);
        a1[4]=f2bf(xr3[0]); a1[5]=f2bf(xr3[1]); a1[6]=f2bf(xr3[2]); a1[7]=f2bf(xr3[3]);
        #pragma unroll
        for (int gg = 0; gg < 4; ++gg)
            acc[gg] = __builtin_amdgcn_mfma_f32_16x16x32_bf16(a0, wx[gg][0], acc[gg], 0, 0, 0);
        #pragma unroll
        for (int gg = 0; gg < 4; ++gg)
            acc[gg] = __builtin_amdgcn_mfma_f32_16x16x32_bf16(a1, wx[gg][1], acc[gg], 0, 0, 0);
    };

    xload(0, 0);   // x for phase A of macro 0

    for (int m = 0; m < SEQ; ++m) {
        #pragma unroll
        for (int ph = 0; ph < 2; ++ph) {
            // ---- x-part for (group 2p+ph, step m) from prefetched regs ----
            xmfma();
            // ---- prefetch x for the NEXT phase (latency hides under this one) ----
            if (ph == 0) xload(1, m); else xload(0, m + 1);

            // ---- poll + h-GEMM: all 16 tagged loads per sweep (one round trip;
            //      data is a full phase old -> first check usually passes) ----
            const unsigned int tg = (unsigned int)m & 0xFFFFu;
            const int buf = (m + 1) & 1;
            const unsigned long long* hp64 = (const unsigned long long*)
                (hx + (((size_t)(2 * p + ph) * 2 + buf) * GB + m16) * HSZ
                    + w * 128 + quad * 8);

            unsigned long long cb[4][4];
            #pragma unroll
            for (int kk = 0; kk < 4; ++kk)
                #pragma unroll
                for (int j = 0; j < 4; ++j) cb[kk][j] = 0ull;

            long long guard = 0;
            for (;;) {
                unsigned int bad = 0;
                if (m16 < 8) {
                    #pragma unroll
                    for (int kk = 0; kk < 4; ++kk)
                        #pragma unroll
                        for (int j = 0; j < 4; ++j) {
                            cb[kk][j] = __hip_atomic_load(hp64 + kk * 16 + j,
                                __ATOMIC_RELAXED, __HIP_MEMORY_SCOPE_AGENT);
                            bad |= ((unsigned int)cb[kk][j] ^ tg)
                                 | ((unsigned int)(cb[kk][j] >> 32) ^ tg);
                        }
                }
                if (__all((int)((bad & 0xFFFFu) == 0u))) break;
                __builtin_amdgcn_s_sleep(1);
                if (++guard > (1LL << 22)) break;   // safety valve (never trips)
            }
            #pragma unroll
            for (int kk = 0; kk < 4; ++kk) {
                bf16x8 ha;
                #pragma unroll
                for (int j = 0; j < 4; ++j) {
                    ha[2 * j]     = (short)((unsigned int)cb[kk][j] >> 16);
                    ha[2 * j + 1] = (short)(cb[kk][j] >> 48);
                }
                #pragma unroll
                for (int gg = 0; gg < 4; ++gg)
                    acc[gg] = __builtin_amdgcn_mfma_f32_16x16x32_bf16(ha, wh[gg][kk], acc[gg], 0, 0, 0);
            }

            // ---- partials -> LDS (D: col = m16, row = quad*4 + r; rows 0-7 real) ----
            if (quad < 2) {
                #pragma unroll
                for (int gg = 0; gg < 4; ++gg)
                    #pragma unroll
                    for (int r = 0; r < 4; ++r)
                        gtile[ph][w][gg][quad * 4 + r][m16] = acc[gg][r];
            }
            __syncthreads();   // one barrier per phase (per step)

            // ---- elementwise gates + publish + out (waves 0-1; waves 2-7
            //      race ahead into the next phase's xmfma/poll) ----
            if (tid < 128) {
                float gv[4];
                #pragma unroll
                for (int gg = 0; gg < 4; ++gg) {
                    float ss = bia[gg];
                    #pragma unroll
                    for (int ww = 0; ww < 8; ++ww)
                        ss += gtile[ph][ww][gg][eb][ec];
                    gv[gg] = ss;
                }
                float f  = sigm(gv[0]);
                float i  = sigm(gv[1]);
                float cc = tanh_fast(gv[2]);
                float o  = sigm(gv[3]);
                float c_new = f * (ph ? c_st1 : c_st0) + i * cc;
                if (ph) c_st1 = c_new; else c_st0 = c_new;
                float h_val = o * tanh_fast(c_new);
                unsigned int pword = ((unsigned int)(unsigned short)f2bf(h_val) << 16)
                                   | ((unsigned int)(m + 1) & 0xFFFFu);
                unsigned int nw = __shfl_xor(pword, 1, 64);
                if (!(ec & 1)) {
                    unsigned long long pk = (unsigned long long)pword
                                          | ((unsigned long long)nw << 32);
                    __hip_atomic_store(
                        (unsigned long long*)(hx
                            + (((size_t)(2 * p + ph) * 2 + (m & 1)) * GB + eb) * HSZ
                            + s * 16 + ec),
                        pk, __ATOMIC_RELAXED, __HIP_MEMORY_SCOPE_AGENT);
                }
                const int batch = (2 * p + ph) * 8 + eb;
                out[((size_t)batch * SEQ + m) * HSZ + s * 16 + ec] = h_val;
                if (m == SEQ - 1) {
                    size_t fin = (size_t)BATCH * SEQ * HSZ;
                    out[fin + (size_t)batch * HSZ + s * 16 + ec] = h_val;
                    out[fin + (size_t)BATCH * HSZ + (size_t)batch * HSZ
                            + s * 16 + ec] = c_new;
                }
            }
        }
    }
}

extern "C" void kernel_launch(void* const* d_in, const int* in_sizes, int n_in,
                              void* d_out, int out_size, void* d_ws, size_t ws_size,
                              hipStream_t stream) {
    const float* x    = (const float*)d_in[0];
    const float* W    = (const float*)d_in[1];
    const float* bias = (const float*)d_in[2];
    float* out        = (float*)d_out;

    unsigned int* hx = (unsigned int*)d_ws;

    // zero tagged exchange: epoch 0 == valid h(-1) = 0 for all groups/buffers
    hipMemsetAsync(d_ws, 0, HEX_DW * 4, stream);

    lstm_persistent<<<256, 512, 0, stream>>>(x, W, bias, out, hx);
}